// Round 4
// baseline (282.802 us; speedup 1.0000x reference)
//
#include <hip/hip_runtime.h>
#include <hip/hip_bf16.h>

#define TT    512
#define ISZ   9
#define HH    50
#define NB    16      // batches per block
#define NWAVE 13      // one 16-row tile per wave
#define NTH   (NWAVE * 64)   // 832 threads
#define KDIM  128
// K layout (bf16 elements, per batch-column):
//   k=2j / 2j+1    : h_j hi / lo   (j = 0..49)      bytes 0..199
//   k=100..103     : dead (j=50,51 spill columns)   bytes 200..207
//   k=104+2i/105+2i: x_i hi / lo   (i = 0..8)       bytes 208..243
//   k=122..127     : zero pad
// Bias is carried in the MFMA C-input (exact f32), not in K.

typedef __bf16 bf16x8_t __attribute__((ext_vector_type(8)));
typedef float  f32x4_t  __attribute__((ext_vector_type(4)));

#define L2E  1.44269504088896340736f

// cold-path exact-RNE bf16 (weights only)
__device__ __forceinline__ unsigned short bf16_rne(float f) {
  unsigned u = __builtin_bit_cast(unsigned, f);
  unsigned r = (u + 0x7FFFu + ((u >> 16) & 1u)) >> 16;
  return (unsigned short)r;
}
// hot-path: hardware converts; hi/lo packed into one u32 (lo in high half)
__device__ __forceinline__ unsigned pack_hilo(float v) {
  __bf16 hi = (__bf16)v;
  float  hf = (float)hi;
  __bf16 lo = (__bf16)(v - hf);
  return ((unsigned)__builtin_bit_cast(unsigned short, lo) << 16) |
         (unsigned)__builtin_bit_cast(unsigned short, hi);
}

__global__ __launch_bounds__(NTH, 1) void lstm_mfma(
    const float* __restrict__ x,
    const float* __restrict__ w_ih,
    const float* __restrict__ w_hh,
    const float* __restrict__ b_ih,
    const float* __restrict__ b_hh,
    const float* __restrict__ fc_w,
    const float* __restrict__ fc_b,
    float* __restrict__ out) {
  __shared__ __align__(16) unsigned short hbuf[2][NB * KDIM];  // 2 x 4096 B
  __shared__ float redbuf[NWAVE][NB];

  const int tid = threadIdx.x;
  const int w   = tid >> 6;          // wave id 0..12 = tile id
  const int l   = tid & 63;
  const int lb  = l & 15;            // batch column
  const int kq  = l >> 4;            // k-quarter 0..3
  const int b0  = blockIdx.x * NB;

  // ---- zero both h buffers
  for (int i = tid; i < (2 * NB * KDIM) / 2; i += NTH)
    reinterpret_cast<unsigned*>(hbuf)[i] = 0u;

  // ---- x(t=0) into buf0
  const int xb = tid / ISZ, xi = tid - xb * ISZ;
  const bool xact = (tid < NB * ISZ);
  __syncthreads();
  if (xact) {
    float xv = x[(size_t)(b0 + xb) * (TT * ISZ) + xi];
    *(unsigned*)((char*)hbuf[0] + (((xb << 8) + 208 + (xi << 2)) ^ ((xb & 7) << 4))) = pack_hilo(xv);
  }

  // ---- static A fragment (one tile per wave), weights pre-scaled:
  //   gates i,f,o (sigmoid): scale -log2e  -> acc = -z*log2e, sigma = rcp(1+exp2(acc))
  //   gate  g     (tanh)   : scale +2log2e -> tanh = 1 - 2*rcp(1+exp2(acc))
  // A layout: lane holds A[row = l&15][k = 8*(l>>4)+e]; row permutation rp=4j+g.
  bf16x8_t afrag[4];
  {
    const int rp   = w * 16 + lb;
    const int jA   = rp >> 2;
    const int gA   = rp & 3;
    const int rowA = gA * HH + jA;
    const bool liveA = (jA < HH);
    const float scA = (gA == 2) ? (2.0f * L2E) : (-L2E);
#pragma unroll
    for (int ks = 0; ks < 4; ++ks) {
#pragma unroll
      for (int e = 0; e < 8; ++e) {
        const int K = ks * 32 + kq * 8 + e;
        unsigned short bits = 0;
        if (liveA) {
          if (K < 2 * HH)                      bits = bf16_rne(w_hh[rowA * HH + (K >> 1)] * scA);
          else if (K >= 104 && K < 104 + 2*ISZ) bits = bf16_rne(w_ih[rowA * ISZ + ((K - 104) >> 1)] * scA);
        }
        afrag[ks][e] = __builtin_bit_cast(__bf16, bits);
      }
    }
  }

  // ---- per-lane bias C-init (exact f32, pre-scaled), cell (j0, lb)
  const int j0 = w * 4 + kq;           // output j of this lane (j0>=50 dead)
  f32x4_t bias0;
#pragma unroll
  for (int r = 0; r < 4; ++r) {
    const float sc = (r == 2) ? (2.0f * L2E) : (-L2E);
    bias0[r] = (j0 < HH) ? (b_ih[r * HH + j0] + b_hh[r * HH + j0]) * sc : 0.0f;
  }

  // ---- precomputed LDS byte addresses (toggle ^0x1000 per step)
  char* const base = (char*)hbuf[0];
  const int swzb = (lb & 7) << 4;
  int rd0 = ((lb << 8) + 0   + (kq << 4)) ^ swzb;
  int rd1 = ((lb << 8) + 64  + (kq << 4)) ^ swzb;
  int rd2 = ((lb << 8) + 128 + (kq << 4)) ^ swzb;
  int rd3 = ((lb << 8) + 192 + (kq << 4)) ^ swzb;
  int wo0 = (((lb << 8) + (j0 << 2)) ^ swzb) + 0x1000;   // j0>=50 lands in dead cols
  int xwo = ((((xb << 8) + 208 + (xi << 2)) ^ ((xb & 7) << 4))) + 0x1000;

  const float* xp = x + (size_t)(b0 + xb) * (TT * ISZ) + xi + ISZ;  // x(t+1)

  float c0 = 0.0f, h0 = 0.0f;

  for (int t = 0; t < TT; ++t) {
    float xv = 0.0f;
    if (xact && (t + 1) < TT) xv = *xp;
    xp += ISZ;

    __syncthreads();   // buf[t&1] now complete

    bf16x8_t bfr0 = *(const bf16x8_t*)(base + rd0);
    bf16x8_t bfr1 = *(const bf16x8_t*)(base + rd1);
    bf16x8_t bfr2 = *(const bf16x8_t*)(base + rd2);
    bf16x8_t bfr3 = *(const bf16x8_t*)(base + rd3);

    f32x4_t acc = bias0;
    acc = __builtin_amdgcn_mfma_f32_16x16x32_bf16(afrag[0], bfr0, acc, 0, 0, 0);
    acc = __builtin_amdgcn_mfma_f32_16x16x32_bf16(afrag[1], bfr1, acc, 0, 0, 0);
    acc = __builtin_amdgcn_mfma_f32_16x16x32_bf16(afrag[2], bfr2, acc, 0, 0, 0);
    acc = __builtin_amdgcn_mfma_f32_16x16x32_bf16(afrag[3], bfr3, acc, 0, 0, 0);

    // acc = (-zi*L2E, -zf*L2E, 2*zg*L2E, -zo*L2E) + scaled bias
    {
      const float iv = __builtin_amdgcn_rcpf(1.0f + __builtin_amdgcn_exp2f(acc[0]));
      const float fv = __builtin_amdgcn_rcpf(1.0f + __builtin_amdgcn_exp2f(acc[1]));
      const float gv = fmaf(-2.0f, __builtin_amdgcn_rcpf(1.0f + __builtin_amdgcn_exp2f(acc[2])), 1.0f);
      const float ov = __builtin_amdgcn_rcpf(1.0f + __builtin_amdgcn_exp2f(acc[3]));
      c0 = fmaf(fv, c0, iv * gv);
      const float tc = fmaf(-2.0f, __builtin_amdgcn_rcpf(1.0f + __builtin_amdgcn_exp2f(c0 * (2.0f * L2E))), 1.0f);
      h0 = ov * tc;
      *(unsigned*)(base + wo0) = pack_hilo(h0);
    }
    if (xact && (t + 1) < TT)
      *(unsigned*)(base + xwo) = pack_hilo(xv);

    rd0 ^= 0x1000; rd1 ^= 0x1000; rd2 ^= 0x1000; rd3 ^= 0x1000;
    wo0 ^= 0x1000; xwo ^= 0x1000;
  }

  // ---- FC epilogue: out[b] = sum_j h_last[j,b]*fc_w[j] + fc_b
  float p = (j0 < HH) ? h0 * fc_w[j0] : 0.0f;
  p += __shfl_xor(p, 16);
  p += __shfl_xor(p, 32);
  if (l < NB) redbuf[w][l] = p;
  __syncthreads();
  if (tid < NB) {
    float a = fc_b[0];
#pragma unroll
    for (int ww = 0; ww < NWAVE; ++ww) a += redbuf[ww][tid];
    out[b0 + tid] = a;
  }
}

extern "C" void kernel_launch(void* const* d_in, const int* in_sizes, int n_in,
                              void* d_out, int out_size, void* d_ws, size_t ws_size,
                              hipStream_t stream) {
  const float* x    = (const float*)d_in[0];
  const float* w_ih = (const float*)d_in[1];
  const float* w_hh = (const float*)d_in[2];
  const float* b_ih = (const float*)d_in[3];
  const float* b_hh = (const float*)d_in[4];
  const float* fc_w = (const float*)d_in[5];
  const float* fc_b = (const float*)d_in[6];
  float* out = (float*)d_out;
  const int Btot = in_sizes[0] / (TT * ISZ);   // 4096
  dim3 grid(Btot / NB), block(NTH);
  hipLaunchKernelGGL(lstm_mfma, grid, block, 0, stream,
                     x, w_ih, w_hh, b_ih, b_hh, fc_w, fc_b, out);
}

// Round 5
// 255.655 us; speedup vs baseline: 1.1062x; 1.1062x over previous
//
#include <hip/hip_runtime.h>
#include <hip/hip_bf16.h>

#define TT    512
#define ISZ   9
#define HH    50
#define NB    16      // batches per block
#define NWAVE 13      // one 16-row tile per wave
#define NTH   (NWAVE * 64)   // 832 threads
#define KDIM  128
// K layout (bf16, per batch-column):
//   k=2j/2j+1     : h_j hi/lo (j=0..49)    bytes 0..199
//   k=100..103    : dead (j=50,51 spill)   bytes 200..207
//   k=104+2i/+1   : x_i hi/lo (i=0..8)     bytes 208..243
//   k=122..127    : zero pad
// Bias is carried in the MFMA C-input (exact f32, pre-scaled).

typedef __bf16 bf16x8_t __attribute__((ext_vector_type(8)));
typedef float  f32x4_t  __attribute__((ext_vector_type(4)));

#define L2E  1.44269504088896340736f

// barrier that drains ONLY lgkmcnt (ds_writes) — vmcnt (x prefetch) stays in flight
#define BAR() asm volatile("s_waitcnt lgkmcnt(0)\n\ts_barrier" ::: "memory")

__device__ __forceinline__ unsigned short bf16_rne(float f) {
  unsigned u = __builtin_bit_cast(unsigned, f);
  unsigned r = (u + 0x7FFFu + ((u >> 16) & 1u)) >> 16;
  return (unsigned short)r;
}
__device__ __forceinline__ unsigned pack_hilo(float v) {
  __bf16 hi = (__bf16)v;
  float  hf = (float)hi;
  __bf16 lo = (__bf16)(v - hf);
  return ((unsigned)__builtin_bit_cast(unsigned short, lo) << 16) |
         (unsigned)__builtin_bit_cast(unsigned short, hi);
}

__global__ __launch_bounds__(NTH, 1) void lstm_mfma(
    const float* __restrict__ x,
    const float* __restrict__ w_ih,
    const float* __restrict__ w_hh,
    const float* __restrict__ b_ih,
    const float* __restrict__ b_hh,
    const float* __restrict__ fc_w,
    const float* __restrict__ fc_b,
    float* __restrict__ out) {
  __shared__ __align__(16) unsigned short hbuf[2][NB * KDIM];  // 2 x 4096 B
  __shared__ float redbuf[NWAVE][NB];

  const int tid = threadIdx.x;
  const int w   = tid >> 6;          // wave id 0..12 = tile id
  const int l   = tid & 63;
  const int lb  = l & 15;            // batch column
  const int kq  = l >> 4;            // k-quarter 0..3
  const int b0  = blockIdx.x * NB;

  // ---- zero both h buffers
  for (int i = tid; i < (2 * NB * KDIM) / 2; i += NTH)
    reinterpret_cast<unsigned*>(hbuf)[i] = 0u;

  const int xb = tid / ISZ, xi = tid - xb * ISZ;
  const bool xact = (tid < NB * ISZ);
  __syncthreads();
  // ---- x(t=0) into buf0
  if (xact) {
    float xv = x[(size_t)(b0 + xb) * (TT * ISZ) + xi];
    *(unsigned*)((char*)hbuf[0] + (((xb << 8) + 208 + (xi << 2)) ^ ((xb & 7) << 4))) = pack_hilo(xv);
  }

  // ---- static A fragment (one tile per wave), weights pre-scaled:
  //   i,f,o rows: * -log2e  -> sigma = rcp(1+exp2(acc))
  //   g row     : * 2log2e  -> tanh  = 1 - 2*rcp(1+exp2(acc))
  // Row permutation rp = 4j+g so lane's 4 acc regs = (i,f,g,o) of one j.
  bf16x8_t afrag[4];
  {
    const int rp   = w * 16 + lb;
    const int jA   = rp >> 2;
    const int gA   = rp & 3;
    const int rowA = gA * HH + jA;
    const bool liveA = (jA < HH);
    const float scA = (gA == 2) ? (2.0f * L2E) : (-L2E);
#pragma unroll
    for (int ks = 0; ks < 4; ++ks) {
#pragma unroll
      for (int e = 0; e < 8; ++e) {
        const int K = ks * 32 + kq * 8 + e;
        unsigned short bits = 0;
        if (liveA) {
          if (K < 2 * HH)                       bits = bf16_rne(w_hh[rowA * HH + (K >> 1)] * scA);
          else if (K >= 104 && K < 104 + 2*ISZ) bits = bf16_rne(w_ih[rowA * ISZ + ((K - 104) >> 1)] * scA);
        }
        afrag[ks][e] = __builtin_bit_cast(__bf16, bits);
      }
    }
  }

  // ---- per-lane bias C-init (exact f32, pre-scaled), cell (j0, lb)
  const int j0 = w * 4 + kq;
  f32x4_t bias0;
#pragma unroll
  for (int r = 0; r < 4; ++r) {
    const float sc = (r == 2) ? (2.0f * L2E) : (-L2E);
    bias0[r] = (j0 < HH) ? (b_ih[r * HH + j0] + b_hh[r * HH + j0]) * sc : 0.0f;
  }

  // ---- loop-invariant LDS byte addresses (buf0-relative; buf1 = +0x1000 imm)
  char* const base = (char*)hbuf[0];
  const int swzb = (lb & 7) << 4;
  const int rd0 = ((lb << 8) + 0   + (kq << 4)) ^ swzb;
  const int rd1 = ((lb << 8) + 64  + (kq << 4)) ^ swzb;
  const int rd2 = ((lb << 8) + 128 + (kq << 4)) ^ swzb;
  const int rd3 = ((lb << 8) + 192 + (kq << 4)) ^ swzb;
  const int wo0 = (((lb << 8) + (j0 << 2)) ^ swzb);          // j0>=50 -> dead cols
  const int xwo = (((xb << 8) + 208 + (xi << 2)) ^ ((xb & 7) << 4));

  const float* xp = x + (size_t)(b0 + xb) * (TT * ISZ) + xi;
  float c0 = 0.0f, h0 = 0.0f;
  // xv_n holds x(t+1); prefetch depth ~1.2 steps
  float xv_n = 0.0f;
  if (xact) xv_n = xp[ISZ];          // x(t=1)
  xp += 2 * ISZ;                     // points at x(t=2)

#define STEP(T, ROFF, WOFF)                                                     \
  {                                                                             \
    float xv_new = 0.0f;                                                        \
    if (xact && (T) + 2 < TT) xv_new = *xp;                                     \
    xp += ISZ;                                                                  \
    BAR();                                                                      \
    bf16x8_t bb0 = *(const bf16x8_t*)(base + rd0 + (ROFF));                     \
    bf16x8_t bb1 = *(const bf16x8_t*)(base + rd1 + (ROFF));                     \
    bf16x8_t bb2 = *(const bf16x8_t*)(base + rd2 + (ROFF));                     \
    bf16x8_t bb3 = *(const bf16x8_t*)(base + rd3 + (ROFF));                     \
    f32x4_t acca = bias0;                                                       \
    f32x4_t accb = {0.f, 0.f, 0.f, 0.f};                                        \
    acca = __builtin_amdgcn_mfma_f32_16x16x32_bf16(afrag[0], bb0, acca, 0,0,0); \
    accb = __builtin_amdgcn_mfma_f32_16x16x32_bf16(afrag[2], bb2, accb, 0,0,0); \
    acca = __builtin_amdgcn_mfma_f32_16x16x32_bf16(afrag[1], bb1, acca, 0,0,0); \
    accb = __builtin_amdgcn_mfma_f32_16x16x32_bf16(afrag[3], bb3, accb, 0,0,0); \
    const float z_i = acca[0] + accb[0];                                        \
    const float z_f = acca[1] + accb[1];                                        \
    const float z_g = acca[2] + accb[2];                                        \
    const float z_o = acca[3] + accb[3];                                        \
    const float iv = __builtin_amdgcn_rcpf(1.0f + __builtin_amdgcn_exp2f(z_i)); \
    const float fv = __builtin_amdgcn_rcpf(1.0f + __builtin_amdgcn_exp2f(z_f)); \
    const float gv = fmaf(-2.0f, __builtin_amdgcn_rcpf(1.0f + __builtin_amdgcn_exp2f(z_g)), 1.0f); \
    const float ov = __builtin_amdgcn_rcpf(1.0f + __builtin_amdgcn_exp2f(z_o)); \
    c0 = fmaf(fv, c0, iv * gv);                                                 \
    const float tc = fmaf(-2.0f, __builtin_amdgcn_rcpf(1.0f + __builtin_amdgcn_exp2f(c0 * (2.0f * L2E))), 1.0f); \
    h0 = ov * tc;                                                               \
    *(unsigned*)(base + wo0 + (WOFF)) = pack_hilo(h0);                          \
    if (xact && (T) + 1 < TT) *(unsigned*)(base + xwo + (WOFF)) = pack_hilo(xv_n); \
    xv_n = xv_new;                                                              \
  }

  for (int t2 = 0; t2 < TT; t2 += 2) {
    STEP(t2,     0x0000, 0x1000);   // read buf0, write buf1
    STEP(t2 + 1, 0x1000, 0x0000);   // read buf1, write buf0
  }
#undef STEP

  // ---- FC epilogue: out[b] = sum_j h_last[j,b]*fc_w[j] + fc_b
  float p = (j0 < HH) ? h0 * fc_w[j0] : 0.0f;
  p += __shfl_xor(p, 16);
  p += __shfl_xor(p, 32);
  if (l < NB) redbuf[w][l] = p;
  __syncthreads();
  if (tid < NB) {
    float a = fc_b[0];
#pragma unroll
    for (int ww = 0; ww < NWAVE; ++ww) a += redbuf[ww][tid];
    out[b0 + tid] = a;
  }
}

extern "C" void kernel_launch(void* const* d_in, const int* in_sizes, int n_in,
                              void* d_out, int out_size, void* d_ws, size_t ws_size,
                              hipStream_t stream) {
  const float* x    = (const float*)d_in[0];
  const float* w_ih = (const float*)d_in[1];
  const float* w_hh = (const float*)d_in[2];
  const float* b_ih = (const float*)d_in[3];
  const float* b_hh = (const float*)d_in[4];
  const float* fc_w = (const float*)d_in[5];
  const float* fc_b = (const float*)d_in[6];
  float* out = (float*)d_out;
  const int Btot = in_sizes[0] / (TT * ISZ);   // 4096
  dim3 grid(Btot / NB), block(NTH);
  hipLaunchKernelGGL(lstm_mfma, grid, block, 0, stream,
                     x, w_ih, w_hh, b_ih, b_hh, fc_w, fc_b, out);
}